// Round 3
// baseline (174.172 us; speedup 1.0000x reference)
//
#include <hip/hip_runtime.h>
#include <stdint.h>

#define HIDDEN 768
#define EMBED  512
#define BATCH  16
#define SEQ    512
#define NWORDS (BATCH*SEQ)      // 8192
#define PAD_FLAT_IDX 2047       // flat index of words[0, 511, 3]
#define NEG_SLOPE 0.1f
#define SA_LD 776               // 768 + 8 ushort pad: frag reads 2-way-only bank aliasing
#define BM 32                   // output rows per block (grid = 256 blocks)

__device__ __forceinline__ unsigned short f2bf(float f) {
    unsigned int x = __float_as_uint(f);
    unsigned int r = x + 0x7fffu + ((x >> 16) & 1u);
    return (unsigned short)(r >> 16);
}

// ---------------------------------------------------------------------------
// Kernel 1 (prep): blocks 0..15 -> per-batch stable-compaction scan writing an
// INVERSE gather descriptor per output row: ids4[row] = nonzero subword ids
// compacted to front (pad row -> {pid}), cnts[row] = #ids to sum.
// blocks 16..399 -> w_ffn [768,512] f32 -> wt [512,768] bf16 N-major.
// ---------------------------------------------------------------------------
__global__ __launch_bounds__(256) void prep_kernel(const int* __restrict__ words,
                                                   const float* __restrict__ w,
                                                   int4* __restrict__ ids4,
                                                   int* __restrict__ cnts,
                                                   unsigned short* __restrict__ wt) {
    if (blockIdx.x < BATCH) {
        int b = blockIdx.x;
        int t = threadIdx.x;          // 0..255; handles words 2t, 2t+1
        int s0 = 2 * t, s1 = 2 * t + 1;
        int4 wa = ((const int4*)words)[b * SEQ + s0];
        int4 wb = ((const int4*)words)[b * SEQ + s1];
        bool v0 = (wa.x | wa.y | wa.z | wa.w) != 0;
        bool v1 = (wb.x | wb.y | wb.z | wb.w) != 0;

        unsigned long long m0 = __ballot(v0);
        unsigned long long m1 = __ballot(v1);
        int lane = t & 63;
        int wave = t >> 6;            // 0..3
        unsigned long long below = (1ull << lane) - 1ull;
        int pre = __popcll(m0 & below) + __popcll(m1 & below);
        __shared__ int wsum[4];
        if (lane == 0) wsum[wave] = __popcll(m0) + __popcll(m1);
        __syncthreads();
        int off = 0, tot = 0;
#pragma unroll
        for (int i = 0; i < 4; ++i) {
            int x = wsum[i];
            if (i < wave) off += x;
            tot += x;
        }
        int vp0 = off + pre;
        int vp1 = vp0 + (v0 ? 1 : 0);
        int d0 = v0 ? vp0 : (tot + (s0 - vp0));   // bijective over [0,SEQ)
        int d1 = v1 ? vp1 : (tot + (s1 - vp1));

        int pid = words[PAD_FLAT_IDX];

        // word s0 -> row b*SEQ+d0
        {
            int id[4] = {wa.x, wa.y, wa.z, wa.w};
            int o[4] = {0, 0, 0, 0};
            int c = 0;
#pragma unroll
            for (int j = 0; j < 4; ++j) if (id[j] != 0) o[c++] = id[j];
            if (c == 0) { o[0] = pid; c = 1; }
            ids4[b * SEQ + d0] = make_int4(o[0], o[1], o[2], o[3]);
            cnts[b * SEQ + d0] = c;
        }
        // word s1 -> row b*SEQ+d1
        {
            int id[4] = {wb.x, wb.y, wb.z, wb.w};
            int o[4] = {0, 0, 0, 0};
            int c = 0;
#pragma unroll
            for (int j = 0; j < 4; ++j) if (id[j] != 0) o[c++] = id[j];
            if (c == 0) { o[0] = pid; c = 1; }
            ids4[b * SEQ + d1] = make_int4(o[0], o[1], o[2], o[3]);
            cnts[b * SEQ + d1] = c;
        }
    } else {
        __shared__ float tile[32][33];
        int bid = blockIdx.x - BATCH;       // 0..383
        int k0 = (bid % (HIDDEN / 32)) * 32;
        int n0 = (bid / (HIDDEN / 32)) * 32;
        int tc = threadIdx.x & 31;
        int tr = threadIdx.x >> 5;          // 0..7
#pragma unroll
        for (int i = 0; i < 4; ++i) {
            int r = tr + i * 8;
            tile[r][tc] = w[(size_t)(k0 + r) * EMBED + n0 + tc];
        }
        __syncthreads();
#pragma unroll
        for (int i = 0; i < 4; ++i) {
            int r = tr + i * 8;             // n offset within tile
            wt[(size_t)(n0 + r) * HIDDEN + k0 + tc] = f2bf(tile[tc][r]);
        }
    }
}

// ---------------------------------------------------------------------------
// Kernel 2 (fused pool + GEMM + bias + LeakyReLU).
// Block = 32 output rows x full EMBED=512 cols. 256 threads = 4 waves.
// Phase 1: gather per-row subword embeddings (via inverse descriptors),
//          mean-pool, bf16 -> padded LDS A-tile (ds_write, pad OK).
// Phase 2: K-loop BK=32: stage B-tile [512x32] via global_load_lds w16
//          (B is L2-resident: 786 KB/XCD), 16 MFMA/wave/iter, acc 2x8.
// Grid 256 blocks -> 1/CU (82 KB LDS). A read ONCE; no xseq round-trip.
// ---------------------------------------------------------------------------
typedef __attribute__((ext_vector_type(8))) short bf16x8;
typedef __attribute__((ext_vector_type(4))) float f32x4;

__device__ __forceinline__ void load_lds16(const void* g, void* l) {
    __builtin_amdgcn_global_load_lds(
        (const __attribute__((address_space(1))) unsigned int*)g,
        (__attribute__((address_space(3))) unsigned int*)l,
        16, 0, 0);
}

__global__ __launch_bounds__(256) void fused_kernel(const int4* __restrict__ ids4,
                                                    const int* __restrict__ cnts,
                                                    const float* __restrict__ table,
                                                    const unsigned short* __restrict__ Bt,
                                                    const float* __restrict__ bias,
                                                    float* __restrict__ out) {
    __shared__ unsigned short sA[BM * SA_LD];   // 49664 B (padded, ds_write-filled)
    __shared__ unsigned short sB[512 * 32];     // 32768 B (global_load_lds-filled)

    int tid  = threadIdx.x;
    int wave = tid >> 6;
    int lane = tid & 63;
    int m0   = blockIdx.x * BM;

    // ---------------- Phase 1: gather + pool into sA ----------------
#pragma unroll 2
    for (int i = 0; i < 8; ++i) {
        int rl  = i * 4 + wave;             // 0..31, wave-uniform
        int row = m0 + rl;
        int4 w4 = ids4[row];
        int cnt = cnts[row];
        int id[4] = {w4.x, w4.y, w4.z, w4.w};
        float sx[3] = {0.f, 0.f, 0.f}, sy[3] = {0.f, 0.f, 0.f};
        float sz[3] = {0.f, 0.f, 0.f}, sw[3] = {0.f, 0.f, 0.f};
#pragma unroll
        for (int j = 0; j < 4; ++j) {
            if (j < cnt) {                  // wave-uniform condition
                const float4* rp = (const float4*)(table + (size_t)id[j] * HIDDEN);
#pragma unroll
                for (int c = 0; c < 3; ++c) {
                    float4 v = rp[lane + 64 * c];
                    sx[c] += v.x; sy[c] += v.y; sz[c] += v.z; sw[c] += v.w;
                }
            }
        }
        float inv = 1.0f / (float)cnt;
#pragma unroll
        for (int c = 0; c < 3; ++c) {
            ushort4 o;
            o.x = f2bf(sx[c] * inv); o.y = f2bf(sy[c] * inv);
            o.z = f2bf(sz[c] * inv); o.w = f2bf(sw[c] * inv);
            *(ushort4*)&sA[rl * SA_LD + (lane + 64 * c) * 4] = o;
        }
    }
    // no barrier yet: first B-stage below only touches sB; the in-loop
    // __syncthreads() (with its vmcnt/lgkmcnt drain) covers sA completeness
    // before any fragment read.

    // ---------------- Phase 2: K-loop GEMM ----------------
    int quad = lane >> 4;
    int l16  = lane & 15;
    f32x4 acc[2][8] = {};

    const unsigned short* gb = Bt + (size_t)(tid >> 2) * HIDDEN + (tid & 3) * 8;

    for (int k0 = 0; k0 < HIDDEN; k0 += 32) {
#pragma unroll
        for (int j = 0; j < 8; ++j)        // rows (tid>>2)+64j, 16 B each
            load_lds16(gb + (size_t)j * 64 * HIDDEN + k0, &sB[(tid + 256 * j) * 8]);
        __syncthreads();

        bf16x8 af[2], bfr[8];
#pragma unroll
        for (int mt = 0; mt < 2; ++mt)
            af[mt] = *(const bf16x8*)&sA[(mt * 16 + l16) * SA_LD + k0 + quad * 8];
#pragma unroll
        for (int nt = 0; nt < 8; ++nt)
            bfr[nt] = *(const bf16x8*)&sB[(wave * 128 + nt * 16 + l16) * 32 + quad * 8];

#pragma unroll
        for (int mt = 0; mt < 2; ++mt)
#pragma unroll
            for (int nt = 0; nt < 8; ++nt)
                acc[mt][nt] = __builtin_amdgcn_mfma_f32_16x16x32_bf16(
                    af[mt], bfr[nt], acc[mt][nt], 0, 0, 0);
        __syncthreads();
    }

    // ---------------- Epilogue: bias + LeakyReLU + store ----------------
#pragma unroll
    for (int nt = 0; nt < 8; ++nt) {
        int col = wave * 128 + nt * 16 + l16;
        float bv = bias[col];
#pragma unroll
        for (int mt = 0; mt < 2; ++mt) {
            int rbase = m0 + mt * 16 + quad * 4;
#pragma unroll
            for (int r = 0; r < 4; ++r) {
                float v = acc[mt][nt][r] + bv;
                v = (v > 0.f) ? v : v * NEG_SLOPE;
                out[(size_t)(rbase + r) * EMBED + col] = v;
            }
        }
    }
}

// ---------------------------------------------------------------------------
extern "C" void kernel_launch(void* const* d_in, const int* in_sizes, int n_in,
                              void* d_out, int out_size, void* d_ws, size_t ws_size,
                              hipStream_t stream) {
    (void)in_sizes; (void)n_in; (void)out_size; (void)ws_size;
    const int*   words = (const int*)d_in[0];
    const float* table = (const float*)d_in[1];
    const float* wffn  = (const float*)d_in[2];
    const float* bffn  = (const float*)d_in[3];
    float* out = (float*)d_out;

    char* ws = (char*)d_ws;
    unsigned short* wt   = (unsigned short*)ws;                  // 786432 B
    int4*           ids4 = (int4*)(ws + 786432);                 // 131072 B
    int*            cnts = (int*)(ws + 786432 + 131072);         //  32768 B

    prep_kernel<<<BATCH + (HIDDEN / 32) * (EMBED / 32), 256, 0, stream>>>(
        words, wffn, ids4, cnts, wt);
    fused_kernel<<<NWORDS / BM, 256, 0, stream>>>(ids4, cnts, table, wt, bffn, out);
}

// Round 4
// 172.333 us; speedup vs baseline: 1.0107x; 1.0107x over previous
//
#include <hip/hip_runtime.h>
#include <stdint.h>

#define HIDDEN 768
#define EMBED  512
#define BATCH  16
#define SEQ    512
#define NWORDS (BATCH*SEQ)      // 8192
#define NKC    (HIDDEN/8)       // 96 chunks of 8 bf16
#define PAD_FLAT_IDX 2047       // flat index of words[0, 511, 3]
#define NEG_SLOPE 0.1f
#define SP_LD 780               // pool LDS leading dim (ushorts): ~2-way banks, x4-aligned

// K-major operand layouts (so GEMM's linear global_load_lds staging yields a
// [q][row] LDS tile with conflict-free b128 fragment reads):
//   xkm: [kc 0..95][row 0..8191][8]  ushort off = kc*65536 + row*8
//   wtk: [kc 0..95][n   0..511][8]  ushort off = kc*4096  + n*8

__device__ __forceinline__ unsigned short f2bf(float f) {
    unsigned int x = __float_as_uint(f);
    unsigned int r = x + 0x7fffu + ((x >> 16) & 1u);
    return (unsigned short)(r >> 16);
}

// ---------------------------------------------------------------------------
// Kernel 1 (prep): blocks 0..15 -> per-batch stable-compaction scan writing
// inverse gather descriptors per OUTPUT row (ids compacted to front; pad row
// -> {pid},cnt=1). blocks 16..399 -> w_ffn [768,512] f32 -> wtk bf16 K-major.
// ---------------------------------------------------------------------------
__global__ __launch_bounds__(256) void prep_kernel(const int* __restrict__ words,
                                                   const float* __restrict__ w,
                                                   int4* __restrict__ ids4,
                                                   int* __restrict__ cnts,
                                                   unsigned short* __restrict__ wtk) {
    if (blockIdx.x < BATCH) {
        int b = blockIdx.x;
        int t = threadIdx.x;          // 0..255; handles words 2t, 2t+1
        int s0 = 2 * t, s1 = 2 * t + 1;
        int4 wa = ((const int4*)words)[b * SEQ + s0];
        int4 wb = ((const int4*)words)[b * SEQ + s1];
        bool v0 = (wa.x | wa.y | wa.z | wa.w) != 0;
        bool v1 = (wb.x | wb.y | wb.z | wb.w) != 0;

        unsigned long long m0 = __ballot(v0);
        unsigned long long m1 = __ballot(v1);
        int lane = t & 63;
        int wave = t >> 6;            // 0..3
        unsigned long long below = (1ull << lane) - 1ull;
        int pre = __popcll(m0 & below) + __popcll(m1 & below);
        __shared__ int wsum[4];
        if (lane == 0) wsum[wave] = __popcll(m0) + __popcll(m1);
        __syncthreads();
        int off = 0, tot = 0;
#pragma unroll
        for (int i = 0; i < 4; ++i) {
            int x = wsum[i];
            if (i < wave) off += x;
            tot += x;
        }
        int vp0 = off + pre;
        int vp1 = vp0 + (v0 ? 1 : 0);
        int d0 = v0 ? vp0 : (tot + (s0 - vp0));   // bijective over [0,SEQ)
        int d1 = v1 ? vp1 : (tot + (s1 - vp1));

        int pid = words[PAD_FLAT_IDX];
        {
            int id[4] = {wa.x, wa.y, wa.z, wa.w};
            int o[4] = {0, 0, 0, 0};
            int c = 0;
#pragma unroll
            for (int j = 0; j < 4; ++j) if (id[j] != 0) o[c++] = id[j];
            if (c == 0) { o[0] = pid; c = 1; }
            ids4[b * SEQ + d0] = make_int4(o[0], o[1], o[2], o[3]);
            cnts[b * SEQ + d0] = c;
        }
        {
            int id[4] = {wb.x, wb.y, wb.z, wb.w};
            int o[4] = {0, 0, 0, 0};
            int c = 0;
#pragma unroll
            for (int j = 0; j < 4; ++j) if (id[j] != 0) o[c++] = id[j];
            if (c == 0) { o[0] = pid; c = 1; }
            ids4[b * SEQ + d1] = make_int4(o[0], o[1], o[2], o[3]);
            cnts[b * SEQ + d1] = c;
        }
    } else {
        // transpose+downcast w[k][n] -> wtk K-major
        __shared__ float tile[32][33];
        int bid = blockIdx.x - BATCH;       // 0..383
        int k0 = (bid % (HIDDEN / 32)) * 32;
        int n0 = (bid / (HIDDEN / 32)) * 32;
        int tc = threadIdx.x & 31;
        int tr = threadIdx.x >> 5;          // 0..7
#pragma unroll
        for (int i = 0; i < 4; ++i) {
            int r = tr + i * 8;
            tile[r][tc] = w[(size_t)(k0 + r) * EMBED + n0 + tc];
        }
        __syncthreads();
        int kc = (k0 >> 3) + (tc >> 3);     // global 8-elt chunk id
        int ko = tc & 7;                    // offset within chunk
#pragma unroll
        for (int i = 0; i < 4; ++i) {
            int n = n0 + tr + i * 8;
            wtk[(size_t)kc * (EMBED * 8) + n * 8 + ko] = f2bf(tile[tc][n - n0]);
        }
    }
}

// ---------------------------------------------------------------------------
// Kernel 2 (pool): 256 blocks x 256 threads; block handles output rows
// m0..m0+31. Phase A: one wave per row (8 rows/wave sequentially): gather
// <=4 table rows (12 independent float4/lane), mean-pool, bf16 -> LDS.
// Phase B: cooperative K-major writeout: per (wave,kc) a contiguous 512 B
// segment of xkm — fully coalesced despite K-major layout.
// ---------------------------------------------------------------------------
__global__ __launch_bounds__(256) void pool_kernel(const int4* __restrict__ ids4,
                                                   const int* __restrict__ cnts,
                                                   const float* __restrict__ table,
                                                   unsigned short* __restrict__ xkm) {
    __shared__ unsigned short sp[32 * SP_LD];   // 49920 B
    int tid  = threadIdx.x;
    int wave = tid >> 6;
    int lane = tid & 63;
    int m0   = blockIdx.x * 32;

#pragma unroll 2
    for (int i = 0; i < 8; ++i) {
        int rl  = i * 4 + wave;             // 0..31, wave-uniform
        int row = m0 + rl;
        int4 w4 = ids4[row];
        int cnt = cnts[row];                // >=1 always (prep guarantees)
        int id[4] = {w4.x, w4.y, w4.z, w4.w};
        float sx[3] = {0.f, 0.f, 0.f}, sy[3] = {0.f, 0.f, 0.f};
        float sz[3] = {0.f, 0.f, 0.f}, sw[3] = {0.f, 0.f, 0.f};
#pragma unroll
        for (int j = 0; j < 4; ++j) {
            if (j < cnt) {                  // wave-uniform: no divergence
                const float4* rp = (const float4*)(table + (size_t)id[j] * HIDDEN);
#pragma unroll
                for (int c = 0; c < 3; ++c) {
                    float4 v = rp[lane + 64 * c];
                    sx[c] += v.x; sy[c] += v.y; sz[c] += v.z; sw[c] += v.w;
                }
            }
        }
        float inv = 1.0f / (float)cnt;
#pragma unroll
        for (int c = 0; c < 3; ++c) {
            ushort4 o;
            o.x = f2bf(sx[c] * inv); o.y = f2bf(sy[c] * inv);
            o.z = f2bf(sz[c] * inv); o.w = f2bf(sw[c] * inv);
            *(ushort4*)&sp[rl * SP_LD + (lane + 64 * c) * 4] = o;
        }
    }
    __syncthreads();

    // writeout: lane -> (row = lane&31, half = lane>>5); per kc: 64x8 B = 512 B
    int rw = lane & 31;
    int hf = lane >> 5;
    for (int kc = wave; kc < NKC; kc += 4) {
        ushort4 v = *(const ushort4*)&sp[rw * SP_LD + kc * 8 + hf * 4];
        *(ushort4*)&xkm[(size_t)kc * (NWORDS * 8) + (m0 + rw) * 8 + hf * 4] = v;
    }
}

// ---------------------------------------------------------------------------
// Kernel 3: C = leaky_relu(A @ B + bias) from K-major bf16 operands.
// Tile 128(M) x 64(N) x 32(K); 256 thr = 4 waves (2x2), wave tile 64x32,
// 8 MFMA 16x16x32/iter. LDS tiles land as [q 0..3][row][8] -> fragment
// b128 reads are conflict-free (banks = row*4 mod 32, 2-way only).
// Grid 64x8 = 512 blocks -> 2/CU.
// ---------------------------------------------------------------------------
typedef __attribute__((ext_vector_type(8))) short bf16x8;
typedef __attribute__((ext_vector_type(4))) float f32x4;

__device__ __forceinline__ void load_lds16(const void* g, void* l) {
    __builtin_amdgcn_global_load_lds(
        (const __attribute__((address_space(1))) unsigned int*)g,
        (__attribute__((address_space(3))) unsigned int*)l,
        16, 0, 0);
}

#define BM 128
#define BN 64
#define BK 32

__global__ __launch_bounds__(256) void gemm_kernel(const unsigned short* __restrict__ xkm,
                                                   const unsigned short* __restrict__ wtk,
                                                   const float* __restrict__ bias,
                                                   float* __restrict__ out) {
    __shared__ unsigned short sA[4 * BM * 8];   // [q][row 0..127][8] = 8 KB
    __shared__ unsigned short sB[4 * BN * 8];   // [q][col 0..63][8]  = 4 KB

    int tid  = threadIdx.x;
    int m0   = blockIdx.x * BM;
    int n0   = blockIdx.y * BN;
    int wave = tid >> 6;
    int lane = tid & 63;
    int wr   = wave >> 1;        // 0..1: 64-row slab
    int wc   = wave & 1;         // 0..1: 32-col slab
    int quad = lane >> 4;        // 0..3
    int l16  = lane & 15;

    f32x4 acc[4][2] = {};

    // staging: A chunk c = tid + 256j -> (q = c>>7, row = c&127)
    //   global ushort off = (k0/8 + q)*NWORDS*8 + (m0+row)*8 = base + k0*8192
    const unsigned short* gA0 = xkm + (size_t)(tid >> 7) * (NWORDS * 8) + (m0 + (tid & 127)) * 8;
    const unsigned short* gA1 = xkm + (size_t)((tid + 256) >> 7) * (NWORDS * 8) + (m0 + ((tid + 256) & 127)) * 8;
    // B chunk c = tid -> (q = tid>>6, col = tid&63); off = base + k0*512
    const unsigned short* gB  = wtk + (size_t)(tid >> 6) * (EMBED * 8) + (n0 + (tid & 63)) * 8;

    for (int k0 = 0; k0 < HIDDEN; k0 += BK) {
        load_lds16(gA0 + (size_t)k0 * (NWORDS), &sA[tid * 8]);
        load_lds16(gA1 + (size_t)k0 * (NWORDS), &sA[(256 + tid) * 8]);
        load_lds16(gB  + (size_t)k0 * (EMBED),  &sB[tid * 8]);
        __syncthreads();

        bf16x8 af[4], bfr[2];
#pragma unroll
        for (int mt = 0; mt < 4; ++mt) {
            int row_l = wr * 64 + mt * 16 + l16;
            af[mt] = *(const bf16x8*)&sA[(quad * BM + row_l) * 8];
        }
#pragma unroll
        for (int nt = 0; nt < 2; ++nt) {
            int col_l = wc * 32 + nt * 16 + l16;
            bfr[nt] = *(const bf16x8*)&sB[(quad * BN + col_l) * 8];
        }

#pragma unroll
        for (int mt = 0; mt < 4; ++mt)
#pragma unroll
            for (int nt = 0; nt < 2; ++nt)
                acc[mt][nt] = __builtin_amdgcn_mfma_f32_16x16x32_bf16(
                    af[mt], bfr[nt], acc[mt][nt], 0, 0, 0);
        __syncthreads();
    }

    // epilogue: D row = quad*4+r, col = l16 (m89/m91-verified layout)
#pragma unroll
    for (int nt = 0; nt < 2; ++nt) {
        int col = n0 + wc * 32 + nt * 16 + l16;
        float bv = bias[col];
#pragma unroll
        for (int mt = 0; mt < 4; ++mt) {
            int rbase = m0 + wr * 64 + mt * 16 + quad * 4;
#pragma unroll
            for (int r = 0; r < 4; ++r) {
                float v = acc[mt][nt][r] + bv;
                v = (v > 0.f) ? v : v * NEG_SLOPE;
                out[(size_t)(rbase + r) * EMBED + col] = v;
            }
        }
    }
}

// ---------------------------------------------------------------------------
extern "C" void kernel_launch(void* const* d_in, const int* in_sizes, int n_in,
                              void* d_out, int out_size, void* d_ws, size_t ws_size,
                              hipStream_t stream) {
    (void)in_sizes; (void)n_in; (void)out_size; (void)ws_size;
    const int*   words = (const int*)d_in[0];
    const float* table = (const float*)d_in[1];
    const float* wffn  = (const float*)d_in[2];
    const float* bffn  = (const float*)d_in[3];
    float* out = (float*)d_out;

    char* ws = (char*)d_ws;
    unsigned short* xkm  = (unsigned short*)ws;                        // 12582912 B
    unsigned short* wtk  = (unsigned short*)(ws + 12582912);           //   786432 B
    int4*           ids4 = (int4*)(ws + 12582912 + 786432);            //   131072 B
    int*            cnts = (int*)(ws + 12582912 + 786432 + 131072);    //    32768 B

    prep_kernel<<<BATCH + (HIDDEN / 32) * (EMBED / 32), 256, 0, stream>>>(
        words, wffn, ids4, cnts, wtk);
    pool_kernel<<<NWORDS / 32, 256, 0, stream>>>(ids4, cnts, table, xkm);
    gemm_kernel<<<dim3(NWORDS / BM, EMBED / BN), 256, 0, stream>>>(xkm, wtk, bffn, out);
}